// Round 1
// baseline (19571.141 us; speedup 1.0000x reference)
//
#include <hip/hip_runtime.h>

#define N_USERS 100000
#define N_ITEMS 50000
#define N_NODES 150000
#define DIM     32
#define N_EDGES 2400000
#define K_STEPS 10

#define NVEC4 (N_NODES * DIM / 4)   // 1.2M float4 groups covering the state

// ---------------- norm reduction: max over rows of sum(x^2) ----------------
__global__ void norm_kernel(const float* __restrict__ xu, const float* __restrict__ xi,
                            unsigned int* __restrict__ norm_bits) {
    int gid = blockIdx.x * blockDim.x + threadIdx.x;
    int row = gid >> 3;      // 8 lanes per row (32 floats = 8 x float4)
    int q   = gid & 7;
    float s = 0.0f;
    if (row < N_NODES) {
        const float* x = (row < N_USERS) ? (xu + (size_t)row * DIM)
                                         : (xi + (size_t)(row - N_USERS) * DIM);
        float4 v = *(const float4*)(x + q * 4);
        s = v.x * v.x + v.y * v.y + v.z * v.z + v.w * v.w;
    }
    // sum within the 8-lane row group
    s += __shfl_xor(s, 1);
    s += __shfl_xor(s, 2);
    s += __shfl_xor(s, 4);
    // max across the wave (rows)
    s = fmaxf(s, __shfl_xor(s, 8));
    s = fmaxf(s, __shfl_xor(s, 16));
    s = fmaxf(s, __shfl_xor(s, 32));
    __shared__ float smax[4];           // 256 threads = 4 waves
    int wave = threadIdx.x >> 6;
    if ((threadIdx.x & 63) == 0) smax[wave] = s;
    __syncthreads();
    if (threadIdx.x == 0) {
        float m = fmaxf(fmaxf(smax[0], smax[1]), fmaxf(smax[2], smax[3]));
        // non-negative floats: uint bit order == float order
        atomicMax(norm_bits, __float_as_uint(m));
    }
}

// ------------- init: h = x / norm (into d_out); zero t1, t2 ----------------
__global__ void init_kernel(const float* __restrict__ xu, const float* __restrict__ xi,
                            const unsigned int* __restrict__ norm_bits,
                            float* __restrict__ h, float* __restrict__ t1, float* __restrict__ t2) {
    int gid = blockIdx.x * blockDim.x + threadIdx.x;
    if (gid >= NVEC4) return;
    float rn = rsqrtf(__uint_as_float(*norm_bits));   // 1/norm
    int idx = gid * 4;
    int row = gid >> 3;                               // (gid*4)/32
    const float* x = (row < N_USERS) ? (xu + idx)
                                     : (xi + (idx - N_USERS * DIM));
    float4 v = *(const float4*)x;
    v.x *= rn; v.y *= rn; v.z *= rn; v.w *= rn;
    *(float4*)(h + idx) = v;
    float4 z = make_float4(0.f, 0.f, 0.f, 0.f);
    *(float4*)(t1 + idx) = z;
    *(float4*)(t2 + idx) = z;
}

// -------- scatter propagation: dst_acc[dst] += w * src_state[src] ----------
// 8 threads per edge, one float4 (16B) slice of the 128B row each.
__global__ void scatter_kernel(const float* __restrict__ src_state,
                               float* __restrict__ dst_acc,
                               const int* __restrict__ es, const int* __restrict__ ed,
                               const float* __restrict__ ew) {
    int gid = blockIdx.x * blockDim.x + threadIdx.x;
    int e = gid >> 3;
    int q = gid & 7;
    if (e >= N_EDGES) return;
    int s = es[e];
    int d = ed[e];
    float w = ew[e];
    float4 v = *(const float4*)(src_state + (size_t)s * DIM + q * 4);
    float* out = dst_acc + (size_t)d * DIM + q * 4;
    atomicAdd(out + 0, v.x * w);
    atomicAdd(out + 1, v.y * w);
    atomicAdd(out + 2, v.z * w);
    atomicAdd(out + 3, v.w * w);
}

// ------ update: h += step*(t2 - sigmoid(alpha)*h + static/norm); zero t ----
__global__ void update_kernel(float* __restrict__ h,
                              const float* __restrict__ su, const float* __restrict__ si,
                              const float* __restrict__ alpha_logit,
                              const float* __restrict__ dt,
                              const unsigned int* __restrict__ norm_bits,
                              float* __restrict__ t1, float* __restrict__ t2) {
    int gid = blockIdx.x * blockDim.x + threadIdx.x;
    if (gid >= NVEC4) return;
    float rn   = rsqrtf(__uint_as_float(*norm_bits));
    float step = dt[0] * (1.0f / K_STEPS);
    int idx = gid * 4;
    int row = gid >> 3;
    float a = 1.0f / (1.0f + __expf(-alpha_logit[row]));
    float4 hv = *(const float4*)(h + idx);
    float4 av = *(const float4*)(t2 + idx);
    const float* st = (row < N_USERS) ? (su + idx) : (si + (idx - N_USERS * DIM));
    float4 sv = *(const float4*)st;
    hv.x += step * (av.x - a * hv.x + sv.x * rn);
    hv.y += step * (av.y - a * hv.y + sv.y * rn);
    hv.z += step * (av.z - a * hv.z + sv.z * rn);
    hv.w += step * (av.w - a * hv.w + sv.w * rn);
    *(float4*)(h + idx) = hv;
    float4 z = make_float4(0.f, 0.f, 0.f, 0.f);
    *(float4*)(t1 + idx) = z;
    *(float4*)(t2 + idx) = z;
}

extern "C" void kernel_launch(void* const* d_in, const int* in_sizes, int n_in,
                              void* d_out, int out_size, void* d_ws, size_t ws_size,
                              hipStream_t stream) {
    const float* xu          = (const float*)d_in[0];
    const float* xi          = (const float*)d_in[1];
    const float* su          = (const float*)d_in[2];
    const float* si          = (const float*)d_in[3];
    const float* ew          = (const float*)d_in[4];
    const float* alpha_logit = (const float*)d_in[5];
    const float* dt          = (const float*)d_in[6];
    const int*   es          = (const int*)d_in[7];
    const int*   ed          = (const int*)d_in[8];
    float* h = (float*)d_out;                       // h lives in the output buffer

    unsigned int* norm_bits = (unsigned int*)d_ws;
    float* t1 = (float*)((char*)d_ws + 256);
    float* t2 = t1 + (size_t)N_NODES * DIM;

    hipMemsetAsync(norm_bits, 0, sizeof(unsigned int), stream);

    {   // norm reduction: 150000 rows * 8 lanes
        int n = N_NODES * 8;
        norm_kernel<<<(n + 255) / 256, 256, 0, stream>>>(xu, xi, norm_bits);
    }
    init_kernel<<<(NVEC4 + 255) / 256, 256, 0, stream>>>(xu, xi, norm_bits, h, t1, t2);

    const int scatter_blocks = (N_EDGES * 8 + 255) / 256;
    const int elem_blocks    = (NVEC4 + 255) / 256;
    for (int k = 0; k < K_STEPS; ++k) {
        scatter_kernel<<<scatter_blocks, 256, 0, stream>>>(h,  t1, es, ed, ew);
        scatter_kernel<<<scatter_blocks, 256, 0, stream>>>(t1, t2, es, ed, ew);
        update_kernel<<<elem_blocks, 256, 0, stream>>>(h, su, si, alpha_logit, dt,
                                                       norm_bits, t1, t2);
    }
}

// Round 2
// 1574.647 us; speedup vs baseline: 12.4289x; 12.4289x over previous
//
#include <hip/hip_runtime.h>

#define N_USERS 100000
#define N_ITEMS 50000
#define N_NODES 150000
#define DIM     32
#define N_EDGES 2400000
#define K_STEPS 10

#define NVEC4 (N_NODES * DIM / 4)       // 1.2M float4 groups covering the state
#define SCAN_CHUNK 1024
#define NB_SCAN ((N_NODES + SCAN_CHUNK - 1) / SCAN_CHUNK)   // 147 blocks

// ---------------- norm reduction: max over rows of sum(x^2) ----------------
__global__ void norm_kernel(const float* __restrict__ xu, const float* __restrict__ xi,
                            unsigned int* __restrict__ norm_bits) {
    int gid = blockIdx.x * blockDim.x + threadIdx.x;
    int row = gid >> 3;      // 8 lanes per row (32 floats = 8 x float4)
    int q   = gid & 7;
    float s = 0.0f;
    if (row < N_NODES) {
        const float* x = (row < N_USERS) ? (xu + (size_t)row * DIM)
                                         : (xi + (size_t)(row - N_USERS) * DIM);
        float4 v = *(const float4*)(x + q * 4);
        s = v.x * v.x + v.y * v.y + v.z * v.z + v.w * v.w;
    }
    s += __shfl_xor(s, 1);
    s += __shfl_xor(s, 2);
    s += __shfl_xor(s, 4);
    s = fmaxf(s, __shfl_xor(s, 8));
    s = fmaxf(s, __shfl_xor(s, 16));
    s = fmaxf(s, __shfl_xor(s, 32));
    __shared__ float smax[4];
    int wave = threadIdx.x >> 6;
    if ((threadIdx.x & 63) == 0) smax[wave] = s;
    __syncthreads();
    if (threadIdx.x == 0) {
        float m = fmaxf(fmaxf(smax[0], smax[1]), fmaxf(smax[2], smax[3]));
        atomicMax(norm_bits, __float_as_uint(m));   // non-neg float: uint order == float order
    }
}

// ------------------- init: h = x / norm (into d_out) -----------------------
__global__ void init_kernel(const float* __restrict__ xu, const float* __restrict__ xi,
                            const unsigned int* __restrict__ norm_bits,
                            float* __restrict__ h) {
    int gid = blockIdx.x * blockDim.x + threadIdx.x;
    if (gid >= NVEC4) return;
    float rn = rsqrtf(__uint_as_float(*norm_bits));   // 1/norm
    int idx = gid * 4;
    int row = gid >> 3;
    const float* x = (row < N_USERS) ? (xu + idx) : (xi + (idx - N_USERS * DIM));
    float4 v = *(const float4*)x;
    v.x *= rn; v.y *= rn; v.z *= rn; v.w *= rn;
    *(float4*)(h + idx) = v;
}

// --------------------------- CSR build: histogram --------------------------
__global__ void hist_kernel(const int* __restrict__ ed, int* __restrict__ deg) {
    int e = blockIdx.x * blockDim.x + threadIdx.x;
    if (e >= N_EDGES) return;
    atomicAdd(&deg[ed[e]], 1);
}

// ------------- CSR build: per-block exclusive scan (1024/block) ------------
__global__ void scan_block_kernel(const int* __restrict__ deg, int* __restrict__ excl,
                                  int* __restrict__ blockSums) {
    int base = blockIdx.x * SCAN_CHUNK + threadIdx.x * 4;
    int v0 = 0, v1 = 0, v2 = 0, v3 = 0;
    if (base + 3 < N_NODES) {
        int4 t = *(const int4*)(deg + base);
        v0 = t.x; v1 = t.y; v2 = t.z; v3 = t.w;
    } else {
        if (base + 0 < N_NODES) v0 = deg[base + 0];
        if (base + 1 < N_NODES) v1 = deg[base + 1];
        if (base + 2 < N_NODES) v2 = deg[base + 2];
    }
    int s = v0 + v1 + v2 + v3;
    int lane = threadIdx.x & 63;
    int inc = s;
    for (int off = 1; off < 64; off <<= 1) {
        int t = __shfl_up(inc, off);
        if (lane >= off) inc += t;
    }
    __shared__ int wsum[4];
    int wave = threadIdx.x >> 6;
    if (lane == 63) wsum[wave] = inc;
    __syncthreads();
    int woff = 0;
    for (int w = 0; w < 4; ++w) if (w < wave) woff += wsum[w];
    int excl_thread = woff + inc - s;
    if (base + 0 < N_NODES) excl[base + 0] = excl_thread;
    if (base + 1 < N_NODES) excl[base + 1] = excl_thread + v0;
    if (base + 2 < N_NODES) excl[base + 2] = excl_thread + v0 + v1;
    if (base + 3 < N_NODES) excl[base + 3] = excl_thread + v0 + v1 + v2;
    if (threadIdx.x == 255) blockSums[blockIdx.x] = woff + inc;  // block total
}

// --------- CSR build: scan the 147 block sums (single 256-thr block) -------
__global__ void scan_sums_kernel(int* __restrict__ blockSums) {
    __shared__ int buf[256];
    int tid = threadIdx.x;
    int v = (tid < NB_SCAN) ? blockSums[tid] : 0;
    buf[tid] = v;
    __syncthreads();
    for (int off = 1; off < 256; off <<= 1) {
        int t = (tid >= off) ? buf[tid - off] : 0;
        __syncthreads();
        buf[tid] += t;
        __syncthreads();
    }
    if (tid < NB_SCAN) blockSums[tid] = buf[tid] - v;   // exclusive
}

// ------------- CSR build: add block offsets -> cursor = row_start ----------
__global__ void add_offsets_kernel(int* __restrict__ cursor, const int* __restrict__ blockSums) {
    int i = blockIdx.x * blockDim.x + threadIdx.x;
    if (i >= N_NODES) return;
    cursor[i] += blockSums[i >> 10];
}

// -- CSR build: bucket fill; cursor advances row_start -> row_end in place --
__global__ void fill_kernel(const int* __restrict__ es, const int* __restrict__ ed,
                            const float* __restrict__ ew,
                            int* __restrict__ cursor, int2* __restrict__ csr) {
    int e = blockIdx.x * blockDim.x + threadIdx.x;
    if (e >= N_EDGES) return;
    int d = ed[e];
    int pos = atomicAdd(&cursor[d], 1);
    csr[pos] = make_int2(es[e], __float_as_int(ew[e]));
}

// -------- gather propagation: out[d] = sum_e w_e * src_state[src_e] --------
// 8 threads per dst node; lane q owns the float4 slice [q*4, q*4+4).
// After fill, cursor[d] == row_end[d]; row_start[d] == row_end[d-1] (dense CSR).
__global__ void gather_kernel(const float* __restrict__ src_state,
                              float* __restrict__ out,
                              const int2* __restrict__ csr,
                              const int* __restrict__ row_end) {
    int gid = blockIdx.x * blockDim.x + threadIdx.x;
    int d = gid >> 3;
    int q = gid & 7;
    if (d >= N_NODES) return;
    int end = row_end[d];
    int beg = (d == 0) ? 0 : row_end[d - 1];
    float4 acc = make_float4(0.f, 0.f, 0.f, 0.f);
    for (int j = beg; j < end; ++j) {
        int2 e = csr[j];
        float w = __int_as_float(e.y);
        float4 v = *(const float4*)(src_state + (size_t)e.x * DIM + (q << 2));
        acc.x = fmaf(w, v.x, acc.x);
        acc.y = fmaf(w, v.y, acc.y);
        acc.z = fmaf(w, v.z, acc.z);
        acc.w = fmaf(w, v.w, acc.w);
    }
    *(float4*)(out + (size_t)d * DIM + (q << 2)) = acc;
}

// ----- hop-2 gather fused with step update:
//       h[d] += step * (P(t1)[d] - sigmoid(alpha[d]) * h[d] + static[d]/norm)
__global__ void gather_update_kernel(const float* __restrict__ t1,
                                     float* __restrict__ h,
                                     const int2* __restrict__ csr,
                                     const int* __restrict__ row_end,
                                     const float* __restrict__ su, const float* __restrict__ si,
                                     const float* __restrict__ alpha_logit,
                                     const float* __restrict__ dt,
                                     const unsigned int* __restrict__ norm_bits) {
    int gid = blockIdx.x * blockDim.x + threadIdx.x;
    int d = gid >> 3;
    int q = gid & 7;
    if (d >= N_NODES) return;
    int end = row_end[d];
    int beg = (d == 0) ? 0 : row_end[d - 1];
    float4 acc = make_float4(0.f, 0.f, 0.f, 0.f);
    for (int j = beg; j < end; ++j) {
        int2 e = csr[j];
        float w = __int_as_float(e.y);
        float4 v = *(const float4*)(t1 + (size_t)e.x * DIM + (q << 2));
        acc.x = fmaf(w, v.x, acc.x);
        acc.y = fmaf(w, v.y, acc.y);
        acc.z = fmaf(w, v.z, acc.z);
        acc.w = fmaf(w, v.w, acc.w);
    }
    float rn   = rsqrtf(__uint_as_float(*norm_bits));
    float step = dt[0] * (1.0f / K_STEPS);
    float a = 1.0f / (1.0f + __expf(-alpha_logit[d]));
    int idx = d * DIM + (q << 2);
    float4 hv = *(const float4*)(h + idx);
    const float* st = (d < N_USERS) ? (su + idx) : (si + (idx - N_USERS * DIM));
    float4 sv = *(const float4*)st;
    hv.x += step * (acc.x - a * hv.x + sv.x * rn);
    hv.y += step * (acc.y - a * hv.y + sv.y * rn);
    hv.z += step * (acc.z - a * hv.z + sv.z * rn);
    hv.w += step * (acc.w - a * hv.w + sv.w * rn);
    *(float4*)(h + idx) = hv;
}

extern "C" void kernel_launch(void* const* d_in, const int* in_sizes, int n_in,
                              void* d_out, int out_size, void* d_ws, size_t ws_size,
                              hipStream_t stream) {
    const float* xu          = (const float*)d_in[0];
    const float* xi          = (const float*)d_in[1];
    const float* su          = (const float*)d_in[2];
    const float* si          = (const float*)d_in[3];
    const float* ew          = (const float*)d_in[4];
    const float* alpha_logit = (const float*)d_in[5];
    const float* dt          = (const float*)d_in[6];
    const int*   es          = (const int*)d_in[7];
    const int*   ed          = (const int*)d_in[8];
    float* h = (float*)d_out;                     // h lives in the output buffer

    // ---- workspace layout (~40.4 MB) ----
    char* base = (char*)d_ws;
    unsigned int* norm_bits = (unsigned int*)base;                 // 4 B
    int*  cursor    = (int*)(base + 1024);                         // 600000 B
    int*  blockSums = cursor + N_NODES;                            // 256 ints
    int*  deg       = blockSums + 256;                             // 600000 B (dead after scan)
    int2* csr       = (int2*)(base + 2u * 1024 * 1024);            // 19.2 MB
    float* t1       = (float*)(base + 2u * 1024 * 1024 + (size_t)N_EDGES * 8);  // 19.2 MB

    hipMemsetAsync(norm_bits, 0, sizeof(unsigned int), stream);
    hipMemsetAsync(deg, 0, (size_t)N_NODES * sizeof(int), stream);

    // norm + init
    norm_kernel<<<(N_NODES * 8 + 255) / 256, 256, 0, stream>>>(xu, xi, norm_bits);
    init_kernel<<<(NVEC4 + 255) / 256, 256, 0, stream>>>(xu, xi, norm_bits, h);

    // CSR build (once per call)
    hist_kernel<<<(N_EDGES + 255) / 256, 256, 0, stream>>>(ed, deg);
    scan_block_kernel<<<NB_SCAN, 256, 0, stream>>>(deg, cursor, blockSums);
    scan_sums_kernel<<<1, 256, 0, stream>>>(blockSums);
    add_offsets_kernel<<<(N_NODES + 255) / 256, 256, 0, stream>>>(cursor, blockSums);
    fill_kernel<<<(N_EDGES + 255) / 256, 256, 0, stream>>>(es, ed, ew, cursor, csr);
    // cursor now holds row_end[]

    const int gather_blocks = (N_NODES * 8 + 255) / 256;
    for (int k = 0; k < K_STEPS; ++k) {
        gather_kernel<<<gather_blocks, 256, 0, stream>>>(h, t1, csr, cursor);
        gather_update_kernel<<<gather_blocks, 256, 0, stream>>>(t1, h, csr, cursor,
                                                                su, si, alpha_logit, dt,
                                                                norm_bits);
    }
}

// Round 3
// 1306.158 us; speedup vs baseline: 14.9838x; 1.2056x over previous
//
#include <hip/hip_runtime.h>

#define N_USERS 100000
#define N_ITEMS 50000
#define N_NODES 150000
#define DIM     32
#define N_EDGES 2400000
#define K_STEPS 10

#define SCAN_CHUNK 1024
#define NB_SCAN ((N_NODES + SCAN_CHUNK - 1) / SCAN_CHUNK)   // 147 blocks
#define WDEQ 3.814697265625e-06f   // 2^-18

// ---------------- helpers: bf16x2 <-> f32 ----------------
__device__ __forceinline__ float bflo(unsigned u) { return __uint_as_float(u << 16); }
__device__ __forceinline__ float bfhi(unsigned u) { return __uint_as_float(u & 0xffff0000u); }
__device__ __forceinline__ unsigned packbf(float a, float b) {   // RNE pack (finite inputs)
    unsigned ua = __float_as_uint(a), ub = __float_as_uint(b);
    ua += 0x7fffu + ((ua >> 16) & 1u);
    ub += 0x7fffu + ((ub >> 16) & 1u);
    return (ua >> 16) | (ub & 0xffff0000u);
}

// ---------------- norm reduction: max over rows of sum(x^2) ----------------
__global__ void norm_kernel(const float* __restrict__ xu, const float* __restrict__ xi,
                            unsigned int* __restrict__ norm_bits) {
    int gid = blockIdx.x * blockDim.x + threadIdx.x;
    int row = gid >> 3;      // 8 lanes per row
    int q   = gid & 7;
    float s = 0.0f;
    if (row < N_NODES) {
        const float* x = (row < N_USERS) ? (xu + (size_t)row * DIM)
                                         : (xi + (size_t)(row - N_USERS) * DIM);
        float4 v = *(const float4*)(x + q * 4);
        s = v.x * v.x + v.y * v.y + v.z * v.z + v.w * v.w;
    }
    s += __shfl_xor(s, 1);
    s += __shfl_xor(s, 2);
    s += __shfl_xor(s, 4);
    s = fmaxf(s, __shfl_xor(s, 8));
    s = fmaxf(s, __shfl_xor(s, 16));
    s = fmaxf(s, __shfl_xor(s, 32));
    __shared__ float smax[4];
    int wave = threadIdx.x >> 6;
    if ((threadIdx.x & 63) == 0) smax[wave] = s;
    __syncthreads();
    if (threadIdx.x == 0) {
        float m = fmaxf(fmaxf(smax[0], smax[1]), fmaxf(smax[2], smax[3]));
        atomicMax(norm_bits, __float_as_uint(m));   // non-neg: uint order == float order
    }
}

// --- init: h = x/norm (fp32 + bf16 mirror); static_bf16 = static/norm ------
// 4 lanes per node; lane q owns floats [q*8, q*8+8).
__global__ void init_kernel(const float* __restrict__ xu, const float* __restrict__ xi,
                            const float* __restrict__ su, const float* __restrict__ si,
                            const unsigned int* __restrict__ norm_bits,
                            float* __restrict__ h, unsigned* __restrict__ h16,
                            unsigned* __restrict__ st16) {
    int gid = blockIdx.x * blockDim.x + threadIdx.x;
    int d = gid >> 2;
    int q = gid & 3;
    if (d >= N_NODES) return;
    float rn = rsqrtf(__uint_as_float(*norm_bits));
    int fbase = d * DIM + q * 8;
    const float* x = (d < N_USERS) ? (xu + fbase) : (xi + fbase - N_USERS * DIM);
    const float* s = (d < N_USERS) ? (su + fbase) : (si + fbase - N_USERS * DIM);
    float4 v0 = *(const float4*)(x);
    float4 v1 = *(const float4*)(x + 4);
    v0.x *= rn; v0.y *= rn; v0.z *= rn; v0.w *= rn;
    v1.x *= rn; v1.y *= rn; v1.z *= rn; v1.w *= rn;
    *(float4*)(h + fbase)     = v0;
    *(float4*)(h + fbase + 4) = v1;
    uint4 hp;
    hp.x = packbf(v0.x, v0.y); hp.y = packbf(v0.z, v0.w);
    hp.z = packbf(v1.x, v1.y); hp.w = packbf(v1.z, v1.w);
    *(uint4*)(h16 + (d << 4) + (q << 2)) = hp;
    float4 s0 = *(const float4*)(s);
    float4 s1 = *(const float4*)(s + 4);
    uint4 sp;
    sp.x = packbf(s0.x * rn, s0.y * rn); sp.y = packbf(s0.z * rn, s0.w * rn);
    sp.z = packbf(s1.x * rn, s1.y * rn); sp.w = packbf(s1.z * rn, s1.w * rn);
    *(uint4*)(st16 + (d << 4) + (q << 2)) = sp;
}

// --------------------------- CSR build: histogram --------------------------
__global__ void hist_kernel(const int* __restrict__ ed, int* __restrict__ deg) {
    int e = blockIdx.x * blockDim.x + threadIdx.x;
    if (e >= N_EDGES) return;
    atomicAdd(&deg[ed[e]], 1);
}

// ------------- CSR build: per-block exclusive scan (1024/block) ------------
__global__ void scan_block_kernel(const int* __restrict__ deg, int* __restrict__ excl,
                                  int* __restrict__ blockSums) {
    int base = blockIdx.x * SCAN_CHUNK + threadIdx.x * 4;
    int v0 = 0, v1 = 0, v2 = 0, v3 = 0;
    if (base + 3 < N_NODES) {
        int4 t = *(const int4*)(deg + base);
        v0 = t.x; v1 = t.y; v2 = t.z; v3 = t.w;
    } else {
        if (base + 0 < N_NODES) v0 = deg[base + 0];
        if (base + 1 < N_NODES) v1 = deg[base + 1];
        if (base + 2 < N_NODES) v2 = deg[base + 2];
    }
    int s = v0 + v1 + v2 + v3;
    int lane = threadIdx.x & 63;
    int inc = s;
    for (int off = 1; off < 64; off <<= 1) {
        int t = __shfl_up(inc, off);
        if (lane >= off) inc += t;
    }
    __shared__ int wsum[4];
    int wave = threadIdx.x >> 6;
    if (lane == 63) wsum[wave] = inc;
    __syncthreads();
    int woff = 0;
    for (int w = 0; w < 4; ++w) if (w < wave) woff += wsum[w];
    int excl_thread = woff + inc - s;
    if (base + 0 < N_NODES) excl[base + 0] = excl_thread;
    if (base + 1 < N_NODES) excl[base + 1] = excl_thread + v0;
    if (base + 2 < N_NODES) excl[base + 2] = excl_thread + v0 + v1;
    if (base + 3 < N_NODES) excl[base + 3] = excl_thread + v0 + v1 + v2;
    if (threadIdx.x == 255) blockSums[blockIdx.x] = woff + inc;
}

// --------- CSR build: scan the 147 block sums (single 256-thr block) -------
__global__ void scan_sums_kernel(int* __restrict__ blockSums) {
    __shared__ int buf[256];
    int tid = threadIdx.x;
    int v = (tid < NB_SCAN) ? blockSums[tid] : 0;
    buf[tid] = v;
    __syncthreads();
    for (int off = 1; off < 256; off <<= 1) {
        int t = (tid >= off) ? buf[tid - off] : 0;
        __syncthreads();
        buf[tid] += t;
        __syncthreads();
    }
    if (tid < NB_SCAN) blockSums[tid] = buf[tid] - v;   // exclusive
}

// ------------- CSR build: add block offsets -> cursor = row_start ----------
__global__ void add_offsets_kernel(int* __restrict__ cursor, const int* __restrict__ blockSums) {
    int i = blockIdx.x * blockDim.x + threadIdx.x;
    if (i >= N_NODES) return;
    cursor[i] += blockSums[i >> 10];
}

// -- CSR build: bucket fill. Entry = (src << 14) | q14, q14 = w * 2^18 ------
__global__ void fill_kernel(const int* __restrict__ es, const int* __restrict__ ed,
                            const float* __restrict__ ew,
                            int* __restrict__ cursor, unsigned* __restrict__ csr) {
    int e = blockIdx.x * blockDim.x + threadIdx.x;
    if (e >= N_EDGES) return;
    int d = ed[e];
    int pos = atomicAdd(&cursor[d], 1);
    unsigned q = (unsigned)(ew[e] * 262144.0f + 0.5f);   // w in [0, 1/16): q < 16384
    if (q > 16383u) q = 16383u;
    csr[pos] = ((unsigned)es[e] << 14) | q;
}

// ------ hop-1 gather: t1_bf16[d] = sum_e w_e * h_bf16[src_e]  (bf16 rows) --
// 4 lanes per node; lane q owns elements [q*8, q*8+8) = uint4 of bf16x2.
__global__ void gather1_kernel(const unsigned* __restrict__ h16,
                               unsigned* __restrict__ t16,
                               const unsigned* __restrict__ csr,
                               const int* __restrict__ row_end) {
    int gid = blockIdx.x * blockDim.x + threadIdx.x;
    int d = gid >> 2;
    int q = gid & 3;
    if (d >= N_NODES) return;
    int end = row_end[d];
    int j = (d == 0) ? 0 : row_end[d - 1];
    float a0 = 0, a1 = 0, a2 = 0, a3 = 0, a4 = 0, a5 = 0, a6 = 0, a7 = 0;
    int qo = q << 2;
    for (; j + 2 <= end; j += 2) {
        unsigned e0 = csr[j], e1 = csr[j + 1];
        float w0 = (float)(e0 & 0x3fffu) * WDEQ;
        float w1 = (float)(e1 & 0x3fffu) * WDEQ;
        uint4 r0 = *(const uint4*)(h16 + ((e0 >> 14) << 4) + qo);
        uint4 r1 = *(const uint4*)(h16 + ((e1 >> 14) << 4) + qo);
        a0 = fmaf(w0, bflo(r0.x), a0); a1 = fmaf(w0, bfhi(r0.x), a1);
        a2 = fmaf(w0, bflo(r0.y), a2); a3 = fmaf(w0, bfhi(r0.y), a3);
        a4 = fmaf(w0, bflo(r0.z), a4); a5 = fmaf(w0, bfhi(r0.z), a5);
        a6 = fmaf(w0, bflo(r0.w), a6); a7 = fmaf(w0, bfhi(r0.w), a7);
        a0 = fmaf(w1, bflo(r1.x), a0); a1 = fmaf(w1, bfhi(r1.x), a1);
        a2 = fmaf(w1, bflo(r1.y), a2); a3 = fmaf(w1, bfhi(r1.y), a3);
        a4 = fmaf(w1, bflo(r1.z), a4); a5 = fmaf(w1, bfhi(r1.z), a5);
        a6 = fmaf(w1, bflo(r1.w), a6); a7 = fmaf(w1, bfhi(r1.w), a7);
    }
    if (j < end) {
        unsigned e0 = csr[j];
        float w0 = (float)(e0 & 0x3fffu) * WDEQ;
        uint4 r0 = *(const uint4*)(h16 + ((e0 >> 14) << 4) + qo);
        a0 = fmaf(w0, bflo(r0.x), a0); a1 = fmaf(w0, bfhi(r0.x), a1);
        a2 = fmaf(w0, bflo(r0.y), a2); a3 = fmaf(w0, bfhi(r0.y), a3);
        a4 = fmaf(w0, bflo(r0.z), a4); a5 = fmaf(w0, bfhi(r0.z), a5);
        a6 = fmaf(w0, bflo(r0.w), a6); a7 = fmaf(w0, bfhi(r0.w), a7);
    }
    uint4 o;
    o.x = packbf(a0, a1); o.y = packbf(a2, a3);
    o.z = packbf(a4, a5); o.w = packbf(a6, a7);
    *(uint4*)(t16 + (d << 4) + qo) = o;
}

// ------ hop-2 gather fused with update:
//   acc = P(t1)[d];  h[d] += step*(acc - sigmoid(alpha[d])*h[d] + static16[d])
//   also refresh h16 mirror for the next step's hop-1.
__global__ void gather2_update_kernel(const unsigned* __restrict__ t16,
                                      float* __restrict__ h,
                                      unsigned* __restrict__ h16,
                                      const unsigned* __restrict__ csr,
                                      const int* __restrict__ row_end,
                                      const unsigned* __restrict__ st16,
                                      const float* __restrict__ alpha_logit,
                                      const float* __restrict__ dt) {
    int gid = blockIdx.x * blockDim.x + threadIdx.x;
    int d = gid >> 2;
    int q = gid & 3;
    if (d >= N_NODES) return;
    int end = row_end[d];
    int j = (d == 0) ? 0 : row_end[d - 1];
    float a0 = 0, a1 = 0, a2 = 0, a3 = 0, a4 = 0, a5 = 0, a6 = 0, a7 = 0;
    int qo = q << 2;
    for (; j + 2 <= end; j += 2) {
        unsigned e0 = csr[j], e1 = csr[j + 1];
        float w0 = (float)(e0 & 0x3fffu) * WDEQ;
        float w1 = (float)(e1 & 0x3fffu) * WDEQ;
        uint4 r0 = *(const uint4*)(t16 + ((e0 >> 14) << 4) + qo);
        uint4 r1 = *(const uint4*)(t16 + ((e1 >> 14) << 4) + qo);
        a0 = fmaf(w0, bflo(r0.x), a0); a1 = fmaf(w0, bfhi(r0.x), a1);
        a2 = fmaf(w0, bflo(r0.y), a2); a3 = fmaf(w0, bfhi(r0.y), a3);
        a4 = fmaf(w0, bflo(r0.z), a4); a5 = fmaf(w0, bfhi(r0.z), a5);
        a6 = fmaf(w0, bflo(r0.w), a6); a7 = fmaf(w0, bfhi(r0.w), a7);
        a0 = fmaf(w1, bflo(r1.x), a0); a1 = fmaf(w1, bfhi(r1.x), a1);
        a2 = fmaf(w1, bflo(r1.y), a2); a3 = fmaf(w1, bfhi(r1.y), a3);
        a4 = fmaf(w1, bflo(r1.z), a4); a5 = fmaf(w1, bfhi(r1.z), a5);
        a6 = fmaf(w1, bflo(r1.w), a6); a7 = fmaf(w1, bfhi(r1.w), a7);
    }
    if (j < end) {
        unsigned e0 = csr[j];
        float w0 = (float)(e0 & 0x3fffu) * WDEQ;
        uint4 r0 = *(const uint4*)(t16 + ((e0 >> 14) << 4) + qo);
        a0 = fmaf(w0, bflo(r0.x), a0); a1 = fmaf(w0, bfhi(r0.x), a1);
        a2 = fmaf(w0, bflo(r0.y), a2); a3 = fmaf(w0, bfhi(r0.y), a3);
        a4 = fmaf(w0, bflo(r0.z), a4); a5 = fmaf(w0, bfhi(r0.z), a5);
        a6 = fmaf(w0, bflo(r0.w), a6); a7 = fmaf(w0, bfhi(r0.w), a7);
    }
    float step = dt[0] * (1.0f / K_STEPS);
    float al = 1.0f / (1.0f + __expf(-alpha_logit[d]));
    int fbase = d * DIM + (q << 3);
    float4 h0 = *(const float4*)(h + fbase);
    float4 h1 = *(const float4*)(h + fbase + 4);
    uint4 sp = *(const uint4*)(st16 + (d << 4) + qo);
    h0.x += step * (a0 - al * h0.x + bflo(sp.x));
    h0.y += step * (a1 - al * h0.y + bfhi(sp.x));
    h0.z += step * (a2 - al * h0.z + bflo(sp.y));
    h0.w += step * (a3 - al * h0.w + bfhi(sp.y));
    h1.x += step * (a4 - al * h1.x + bflo(sp.z));
    h1.y += step * (a5 - al * h1.y + bfhi(sp.z));
    h1.z += step * (a6 - al * h1.z + bflo(sp.w));
    h1.w += step * (a7 - al * h1.w + bfhi(sp.w));
    *(float4*)(h + fbase)     = h0;
    *(float4*)(h + fbase + 4) = h1;
    uint4 hp;
    hp.x = packbf(h0.x, h0.y); hp.y = packbf(h0.z, h0.w);
    hp.z = packbf(h1.x, h1.y); hp.w = packbf(h1.z, h1.w);
    *(uint4*)(h16 + (d << 4) + qo) = hp;
}

extern "C" void kernel_launch(void* const* d_in, const int* in_sizes, int n_in,
                              void* d_out, int out_size, void* d_ws, size_t ws_size,
                              hipStream_t stream) {
    const float* xu          = (const float*)d_in[0];
    const float* xi          = (const float*)d_in[1];
    const float* su          = (const float*)d_in[2];
    const float* si          = (const float*)d_in[3];
    const float* ew          = (const float*)d_in[4];
    const float* alpha_logit = (const float*)d_in[5];
    const float* dt          = (const float*)d_in[6];
    const int*   es          = (const int*)d_in[7];
    const int*   ed          = (const int*)d_in[8];
    float* h = (float*)d_out;                     // h lives in the output buffer

    // ---- workspace layout (~40.4 MB) ----
    char* base = (char*)d_ws;
    unsigned int* norm_bits = (unsigned int*)base;                    // 4 B
    int*  cursor    = (int*)(base + 1024);                            // 600 KB
    int*  blockSums = cursor + N_NODES;                               // 256 ints
    int*  deg       = blockSums + 256;                                // 600 KB
    unsigned* csr   = (unsigned*)(base + 2u * 1024 * 1024);           // 9.6 MB
    unsigned* t16   = csr + N_EDGES;                                  // 9.6 MB
    unsigned* h16   = t16 + (size_t)N_NODES * 16;                     // 9.6 MB
    unsigned* st16  = h16 + (size_t)N_NODES * 16;                     // 9.6 MB

    hipMemsetAsync(norm_bits, 0, sizeof(unsigned int), stream);
    hipMemsetAsync(deg, 0, (size_t)N_NODES * sizeof(int), stream);

    norm_kernel<<<(N_NODES * 8 + 255) / 256, 256, 0, stream>>>(xu, xi, norm_bits);
    init_kernel<<<(N_NODES * 4 + 255) / 256, 256, 0, stream>>>(xu, xi, su, si,
                                                               norm_bits, h, h16, st16);

    // CSR build (once per call)
    hist_kernel<<<(N_EDGES + 255) / 256, 256, 0, stream>>>(ed, deg);
    scan_block_kernel<<<NB_SCAN, 256, 0, stream>>>(deg, cursor, blockSums);
    scan_sums_kernel<<<1, 256, 0, stream>>>(blockSums);
    add_offsets_kernel<<<(N_NODES + 255) / 256, 256, 0, stream>>>(cursor, blockSums);
    fill_kernel<<<(N_EDGES + 255) / 256, 256, 0, stream>>>(es, ed, ew, cursor, csr);
    // cursor now holds row_end[]

    const int gather_blocks = (N_NODES * 4 + 255) / 256;
    for (int k = 0; k < K_STEPS; ++k) {
        gather1_kernel<<<gather_blocks, 256, 0, stream>>>(h16, t16, csr, cursor);
        gather2_update_kernel<<<gather_blocks, 256, 0, stream>>>(t16, h, h16, csr, cursor,
                                                                 st16, alpha_logit, dt);
    }
}

// Round 4
// 1303.536 us; speedup vs baseline: 15.0139x; 1.0020x over previous
//
#include <hip/hip_runtime.h>

#define N_USERS 100000
#define N_ITEMS 50000
#define N_NODES 150000
#define DIM     32
#define N_EDGES 2400000
#define K_STEPS 10

#define SCAN_CHUNK 1024
#define NB_SCAN ((N_NODES + SCAN_CHUNK - 1) / SCAN_CHUNK)   // 147 blocks
#define WDEQ 3.814697265625e-06f   // 2^-18

// ---------------- helpers: bf16x2 <-> f32 ----------------
__device__ __forceinline__ float bflo(unsigned u) { return __uint_as_float(u << 16); }
__device__ __forceinline__ float bfhi(unsigned u) { return __uint_as_float(u & 0xffff0000u); }
__device__ __forceinline__ unsigned packbf(float a, float b) {   // RNE pack (finite inputs)
    unsigned ua = __float_as_uint(a), ub = __float_as_uint(b);
    ua += 0x7fffu + ((ua >> 16) & 1u);
    ub += 0x7fffu + ((ub >> 16) & 1u);
    return (ua >> 16) | (ub & 0xffff0000u);
}

// ---------------- norm reduction: max over rows of sum(x^2) ----------------
__global__ void norm_kernel(const float* __restrict__ xu, const float* __restrict__ xi,
                            unsigned int* __restrict__ norm_bits) {
    int gid = blockIdx.x * blockDim.x + threadIdx.x;
    int row = gid >> 3;
    int q   = gid & 7;
    float s = 0.0f;
    if (row < N_NODES) {
        const float* x = (row < N_USERS) ? (xu + (size_t)row * DIM)
                                         : (xi + (size_t)(row - N_USERS) * DIM);
        float4 v = *(const float4*)(x + q * 4);
        s = v.x * v.x + v.y * v.y + v.z * v.z + v.w * v.w;
    }
    s += __shfl_xor(s, 1);
    s += __shfl_xor(s, 2);
    s += __shfl_xor(s, 4);
    s = fmaxf(s, __shfl_xor(s, 8));
    s = fmaxf(s, __shfl_xor(s, 16));
    s = fmaxf(s, __shfl_xor(s, 32));
    __shared__ float smax[4];
    int wave = threadIdx.x >> 6;
    if ((threadIdx.x & 63) == 0) smax[wave] = s;
    __syncthreads();
    if (threadIdx.x == 0) {
        float m = fmaxf(fmaxf(smax[0], smax[1]), fmaxf(smax[2], smax[3]));
        atomicMax(norm_bits, __float_as_uint(m));   // non-neg: uint order == float order
    }
}

// --------------------------- degree histogram ------------------------------
__global__ void hist_kernel(const int* __restrict__ ed, int* __restrict__ deg) {
    int e = blockIdx.x * blockDim.x + threadIdx.x;
    if (e >= N_EDGES) return;
    atomicAdd(&deg[ed[e]], 1);
}

// ----------------- degree-bucket counts (64 buckets) -----------------------
__global__ void degcnt_kernel(const int* __restrict__ deg, int* __restrict__ cnt) {
    __shared__ int lc[64];
    if (threadIdx.x < 64) lc[threadIdx.x] = 0;
    __syncthreads();
    int d = blockIdx.x * blockDim.x + threadIdx.x;
    if (d < N_NODES) {
        int dg = deg[d];
        atomicAdd(&lc[dg > 63 ? 63 : dg], 1);
    }
    __syncthreads();
    if (threadIdx.x < 64 && lc[threadIdx.x]) atomicAdd(&cnt[threadIdx.x], lc[threadIdx.x]);
}

// ------------- exclusive scan of the 64 bucket counts (1 wave) -------------
__global__ void scan_cnt_kernel(int* __restrict__ cnt) {
    int tid = threadIdx.x;          // 64 threads = 1 wave
    int v = cnt[tid];
    int inc = v;
    for (int off = 1; off < 64; off <<= 1) {
        int t = __shfl_up(inc, off);
        if (tid >= off) inc += t;
    }
    cnt[tid] = inc - v;             // exclusive offset; ticket advances it
}

// --- ticket: degree-sorted permutation. perm[pos]=node, pindex[node]=pos ---
__global__ void ticket_kernel(const int* __restrict__ deg, int* __restrict__ cnt,
                              int* __restrict__ perm, int* __restrict__ pindex,
                              int* __restrict__ pdeg, float* __restrict__ alphap,
                              const float* __restrict__ alpha_logit) {
    __shared__ int lcnt[64];
    __shared__ int lbase[64];
    int tid = threadIdx.x;
    if (tid < 64) lcnt[tid] = 0;
    __syncthreads();
    int d = blockIdx.x * blockDim.x + tid;
    int b = 0, rank = 0, dg = 0;
    if (d < N_NODES) {
        dg = deg[d];
        b = dg > 63 ? 63 : dg;
        rank = atomicAdd(&lcnt[b], 1);
    }
    __syncthreads();
    if (tid < 64 && lcnt[tid]) lbase[tid] = atomicAdd(&cnt[tid], lcnt[tid]);
    __syncthreads();
    if (d < N_NODES) {
        int pos = lbase[b] + rank;
        perm[pos] = d;
        pindex[d] = pos;
        pdeg[pos] = dg;
        alphap[pos] = 1.0f / (1.0f + __expf(-alpha_logit[d]));
    }
}

// ------------- per-block exclusive scan over pdeg (1024/block) -------------
__global__ void scan_block_kernel(const int* __restrict__ pdeg, int* __restrict__ excl,
                                  int* __restrict__ blockSums) {
    int base = blockIdx.x * SCAN_CHUNK + threadIdx.x * 4;
    int v0 = 0, v1 = 0, v2 = 0, v3 = 0;
    if (base + 3 < N_NODES) {
        int4 t = *(const int4*)(pdeg + base);
        v0 = t.x; v1 = t.y; v2 = t.z; v3 = t.w;
    } else {
        if (base + 0 < N_NODES) v0 = pdeg[base + 0];
        if (base + 1 < N_NODES) v1 = pdeg[base + 1];
        if (base + 2 < N_NODES) v2 = pdeg[base + 2];
    }
    int s = v0 + v1 + v2 + v3;
    int lane = threadIdx.x & 63;
    int inc = s;
    for (int off = 1; off < 64; off <<= 1) {
        int t = __shfl_up(inc, off);
        if (lane >= off) inc += t;
    }
    __shared__ int wsum[4];
    int wave = threadIdx.x >> 6;
    if (lane == 63) wsum[wave] = inc;
    __syncthreads();
    int woff = 0;
    for (int w = 0; w < 4; ++w) if (w < wave) woff += wsum[w];
    int excl_thread = woff + inc - s;
    if (base + 0 < N_NODES) excl[base + 0] = excl_thread;
    if (base + 1 < N_NODES) excl[base + 1] = excl_thread + v0;
    if (base + 2 < N_NODES) excl[base + 2] = excl_thread + v0 + v1;
    if (base + 3 < N_NODES) excl[base + 3] = excl_thread + v0 + v1 + v2;
    if (threadIdx.x == 255) blockSums[blockIdx.x] = woff + inc;
}

__global__ void scan_sums_kernel(int* __restrict__ blockSums) {
    __shared__ int buf[256];
    int tid = threadIdx.x;
    int v = (tid < NB_SCAN) ? blockSums[tid] : 0;
    buf[tid] = v;
    __syncthreads();
    for (int off = 1; off < 256; off <<= 1) {
        int t = (tid >= off) ? buf[tid - off] : 0;
        __syncthreads();
        buf[tid] += t;
        __syncthreads();
    }
    if (tid < NB_SCAN) blockSums[tid] = buf[tid] - v;   // exclusive
}

// prow[i] += blockoffset; sentinel prow[N_NODES] = N_EDGES
__global__ void add_offsets_kernel(int* __restrict__ prow, const int* __restrict__ blockSums) {
    int i = blockIdx.x * blockDim.x + threadIdx.x;
    if (i == 0) prow[N_NODES] = N_EDGES;
    if (i >= N_NODES) return;
    prow[i] += blockSums[i >> 10];
}

// node_cursor[node] = permuted row start (for fill's ticketing)
__global__ void nodestart_kernel(const int* __restrict__ perm, const int* __restrict__ prow,
                                 int* __restrict__ node_cursor) {
    int i = blockIdx.x * blockDim.x + threadIdx.x;
    if (i >= N_NODES) return;
    node_cursor[perm[i]] = prow[i];
}

// --- init: h(d_out, node order) = x/norm; permuted bf16 mirrors h16p/st16p -
__global__ void init_kernel(const float* __restrict__ xu, const float* __restrict__ xi,
                            const float* __restrict__ su, const float* __restrict__ si,
                            const unsigned int* __restrict__ norm_bits,
                            const int* __restrict__ pindex,
                            float* __restrict__ h, unsigned* __restrict__ h16p,
                            unsigned* __restrict__ st16p) {
    int gid = blockIdx.x * blockDim.x + threadIdx.x;
    int d = gid >> 2;
    int q = gid & 3;
    if (d >= N_NODES) return;
    float rn = rsqrtf(__uint_as_float(*norm_bits));
    int fbase = d * DIM + q * 8;
    const float* x = (d < N_USERS) ? (xu + fbase) : (xi + fbase - N_USERS * DIM);
    const float* s = (d < N_USERS) ? (su + fbase) : (si + fbase - N_USERS * DIM);
    float4 v0 = *(const float4*)(x);
    float4 v1 = *(const float4*)(x + 4);
    v0.x *= rn; v0.y *= rn; v0.z *= rn; v0.w *= rn;
    v1.x *= rn; v1.y *= rn; v1.z *= rn; v1.w *= rn;
    *(float4*)(h + fbase)     = v0;
    *(float4*)(h + fbase + 4) = v1;
    int i = pindex[d];
    uint4 hp;
    hp.x = packbf(v0.x, v0.y); hp.y = packbf(v0.z, v0.w);
    hp.z = packbf(v1.x, v1.y); hp.w = packbf(v1.z, v1.w);
    *(uint4*)(h16p + (i << 4) + (q << 2)) = hp;
    float4 s0 = *(const float4*)(s);
    float4 s1 = *(const float4*)(s + 4);
    uint4 sp;
    sp.x = packbf(s0.x * rn, s0.y * rn); sp.y = packbf(s0.z * rn, s0.w * rn);
    sp.z = packbf(s1.x * rn, s1.y * rn); sp.w = packbf(s1.z * rn, s1.w * rn);
    *(uint4*)(st16p + (i << 4) + (q << 2)) = sp;
}

// -- fill: CSR entry = (pindex[src] << 14) | q14 at permuted row position ---
__global__ void fill_kernel(const int* __restrict__ es, const int* __restrict__ ed,
                            const float* __restrict__ ew, const int* __restrict__ pindex,
                            int* __restrict__ node_cursor, unsigned* __restrict__ csr) {
    int e = blockIdx.x * blockDim.x + threadIdx.x;
    if (e >= N_EDGES) return;
    int d = ed[e];
    int pos = atomicAdd(&node_cursor[d], 1);
    unsigned q = (unsigned)(ew[e] * 262144.0f + 0.5f);   // w in [0,1/16): q < 16384
    if (q > 16383u) q = 16383u;
    csr[pos] = ((unsigned)pindex[es[e]] << 14) | q;
}

// ---- hop-1 gather over permuted rows: t16p[i] = sum w * h16p[psrc] --------
__global__ void gather1_kernel(const unsigned* __restrict__ h16p,
                               unsigned* __restrict__ t16p,
                               const unsigned* __restrict__ csr,
                               const int* __restrict__ prow) {
    int gid = blockIdx.x * blockDim.x + threadIdx.x;
    int i = gid >> 2;
    int q = gid & 3;
    if (i >= N_NODES) return;
    int j   = prow[i];
    int end = prow[i + 1];
    float a0 = 0, a1 = 0, a2 = 0, a3 = 0, a4 = 0, a5 = 0, a6 = 0, a7 = 0;
    int qo = q << 2;
    for (; j + 2 <= end; j += 2) {
        unsigned e0 = csr[j], e1 = csr[j + 1];
        float w0 = (float)(e0 & 0x3fffu) * WDEQ;
        float w1 = (float)(e1 & 0x3fffu) * WDEQ;
        uint4 r0 = *(const uint4*)(h16p + ((e0 >> 14) << 4) + qo);
        uint4 r1 = *(const uint4*)(h16p + ((e1 >> 14) << 4) + qo);
        a0 = fmaf(w0, bflo(r0.x), a0); a1 = fmaf(w0, bfhi(r0.x), a1);
        a2 = fmaf(w0, bflo(r0.y), a2); a3 = fmaf(w0, bfhi(r0.y), a3);
        a4 = fmaf(w0, bflo(r0.z), a4); a5 = fmaf(w0, bfhi(r0.z), a5);
        a6 = fmaf(w0, bflo(r0.w), a6); a7 = fmaf(w0, bfhi(r0.w), a7);
        a0 = fmaf(w1, bflo(r1.x), a0); a1 = fmaf(w1, bfhi(r1.x), a1);
        a2 = fmaf(w1, bflo(r1.y), a2); a3 = fmaf(w1, bfhi(r1.y), a3);
        a4 = fmaf(w1, bflo(r1.z), a4); a5 = fmaf(w1, bfhi(r1.z), a5);
        a6 = fmaf(w1, bflo(r1.w), a6); a7 = fmaf(w1, bfhi(r1.w), a7);
    }
    if (j < end) {
        unsigned e0 = csr[j];
        float w0 = (float)(e0 & 0x3fffu) * WDEQ;
        uint4 r0 = *(const uint4*)(h16p + ((e0 >> 14) << 4) + qo);
        a0 = fmaf(w0, bflo(r0.x), a0); a1 = fmaf(w0, bfhi(r0.x), a1);
        a2 = fmaf(w0, bflo(r0.y), a2); a3 = fmaf(w0, bfhi(r0.y), a3);
        a4 = fmaf(w0, bflo(r0.z), a4); a5 = fmaf(w0, bfhi(r0.z), a5);
        a6 = fmaf(w0, bflo(r0.w), a6); a7 = fmaf(w0, bfhi(r0.w), a7);
    }
    uint4 o;
    o.x = packbf(a0, a1); o.y = packbf(a2, a3);
    o.z = packbf(a4, a5); o.w = packbf(a6, a7);
    *(uint4*)(t16p + (i << 4) + qo) = o;
}

// ---- hop-2 gather + update over permuted rows; h stays node-indexed -------
__global__ void gather2_update_kernel(const unsigned* __restrict__ t16p,
                                      float* __restrict__ h,
                                      unsigned* __restrict__ h16p,
                                      const unsigned* __restrict__ csr,
                                      const int* __restrict__ prow,
                                      const int* __restrict__ perm,
                                      const unsigned* __restrict__ st16p,
                                      const float* __restrict__ alphap,
                                      const float* __restrict__ dt) {
    int gid = blockIdx.x * blockDim.x + threadIdx.x;
    int i = gid >> 2;
    int q = gid & 3;
    if (i >= N_NODES) return;
    int j   = prow[i];
    int end = prow[i + 1];
    float a0 = 0, a1 = 0, a2 = 0, a3 = 0, a4 = 0, a5 = 0, a6 = 0, a7 = 0;
    int qo = q << 2;
    for (; j + 2 <= end; j += 2) {
        unsigned e0 = csr[j], e1 = csr[j + 1];
        float w0 = (float)(e0 & 0x3fffu) * WDEQ;
        float w1 = (float)(e1 & 0x3fffu) * WDEQ;
        uint4 r0 = *(const uint4*)(t16p + ((e0 >> 14) << 4) + qo);
        uint4 r1 = *(const uint4*)(t16p + ((e1 >> 14) << 4) + qo);
        a0 = fmaf(w0, bflo(r0.x), a0); a1 = fmaf(w0, bfhi(r0.x), a1);
        a2 = fmaf(w0, bflo(r0.y), a2); a3 = fmaf(w0, bfhi(r0.y), a3);
        a4 = fmaf(w0, bflo(r0.z), a4); a5 = fmaf(w0, bfhi(r0.z), a5);
        a6 = fmaf(w0, bflo(r0.w), a6); a7 = fmaf(w0, bfhi(r0.w), a7);
        a0 = fmaf(w1, bflo(r1.x), a0); a1 = fmaf(w1, bfhi(r1.x), a1);
        a2 = fmaf(w1, bflo(r1.y), a2); a3 = fmaf(w1, bfhi(r1.y), a3);
        a4 = fmaf(w1, bflo(r1.z), a4); a5 = fmaf(w1, bfhi(r1.z), a5);
        a6 = fmaf(w1, bflo(r1.w), a6); a7 = fmaf(w1, bfhi(r1.w), a7);
    }
    if (j < end) {
        unsigned e0 = csr[j];
        float w0 = (float)(e0 & 0x3fffu) * WDEQ;
        uint4 r0 = *(const uint4*)(t16p + ((e0 >> 14) << 4) + qo);
        a0 = fmaf(w0, bflo(r0.x), a0); a1 = fmaf(w0, bfhi(r0.x), a1);
        a2 = fmaf(w0, bflo(r0.y), a2); a3 = fmaf(w0, bfhi(r0.y), a3);
        a4 = fmaf(w0, bflo(r0.z), a4); a5 = fmaf(w0, bfhi(r0.z), a5);
        a6 = fmaf(w0, bflo(r0.w), a6); a7 = fmaf(w0, bfhi(r0.w), a7);
    }
    float step = dt[0] * (1.0f / K_STEPS);
    float al = alphap[i];
    int d = perm[i];
    int fbase = d * DIM + (q << 3);
    float4 h0 = *(const float4*)(h + fbase);
    float4 h1 = *(const float4*)(h + fbase + 4);
    uint4 sp = *(const uint4*)(st16p + (i << 4) + qo);
    h0.x += step * (a0 - al * h0.x + bflo(sp.x));
    h0.y += step * (a1 - al * h0.y + bfhi(sp.x));
    h0.z += step * (a2 - al * h0.z + bflo(sp.y));
    h0.w += step * (a3 - al * h0.w + bfhi(sp.y));
    h1.x += step * (a4 - al * h1.x + bflo(sp.z));
    h1.y += step * (a5 - al * h1.y + bfhi(sp.z));
    h1.z += step * (a6 - al * h1.z + bflo(sp.w));
    h1.w += step * (a7 - al * h1.w + bfhi(sp.w));
    *(float4*)(h + fbase)     = h0;
    *(float4*)(h + fbase + 4) = h1;
    uint4 hp;
    hp.x = packbf(h0.x, h0.y); hp.y = packbf(h0.z, h0.w);
    hp.z = packbf(h1.x, h1.y); hp.w = packbf(h1.z, h1.w);
    *(uint4*)(h16p + (i << 4) + qo) = hp;
}

extern "C" void kernel_launch(void* const* d_in, const int* in_sizes, int n_in,
                              void* d_out, int out_size, void* d_ws, size_t ws_size,
                              hipStream_t stream) {
    const float* xu          = (const float*)d_in[0];
    const float* xi          = (const float*)d_in[1];
    const float* su          = (const float*)d_in[2];
    const float* si          = (const float*)d_in[3];
    const float* ew          = (const float*)d_in[4];
    const float* alpha_logit = (const float*)d_in[5];
    const float* dt          = (const float*)d_in[6];
    const int*   es          = (const int*)d_in[7];
    const int*   ed          = (const int*)d_in[8];
    float* h = (float*)d_out;                     // fp32 h lives in d_out (node order)

    // ---- workspace layout (~43.4 MB) ----
    char* base = (char*)d_ws;
    unsigned int* norm_bits = (unsigned int*)base;              // 4 B
    int* cnt       = (int*)(base + 64);                         // 64 ints
    int* blockSums = (int*)(base + 512);                        // 256 ints
    const size_t SLOT = 640 * 1024;                             // 640 KB slots
    int*   deg         = (int*)(base + 4096 + 0 * SLOT);
    int*   perm        = (int*)(base + 4096 + 1 * SLOT);
    int*   pindex      = (int*)(base + 4096 + 2 * SLOT);
    int*   pdeg        = (int*)(base + 4096 + 3 * SLOT);
    int*   prow        = (int*)(base + 4096 + 4 * SLOT);        // N_NODES+1 entries
    int*   node_cursor = (int*)(base + 4096 + 5 * SLOT);
    float* alphap      = (float*)(base + 4096 + 6 * SLOT);
    unsigned* csr   = (unsigned*)(base + 5u * 1024 * 1024);     // 9.6 MB
    unsigned* t16p  = csr  + N_EDGES;                           // 9.6 MB
    unsigned* h16p  = t16p + (size_t)N_NODES * 16;              // 9.6 MB
    unsigned* st16p = h16p + (size_t)N_NODES * 16;              // 9.6 MB

    hipMemsetAsync(norm_bits, 0, sizeof(unsigned int), stream);
    hipMemsetAsync(cnt, 0, 64 * sizeof(int), stream);
    hipMemsetAsync(deg, 0, (size_t)N_NODES * sizeof(int), stream);

    const int nodeb  = (N_NODES + 255) / 256;
    const int edgeb  = (N_EDGES + 255) / 256;
    const int node4b = (N_NODES * 4 + 255) / 256;

    norm_kernel<<<(N_NODES * 8 + 255) / 256, 256, 0, stream>>>(xu, xi, norm_bits);
    hist_kernel<<<edgeb, 256, 0, stream>>>(ed, deg);
    degcnt_kernel<<<nodeb, 256, 0, stream>>>(deg, cnt);
    scan_cnt_kernel<<<1, 64, 0, stream>>>(cnt);
    ticket_kernel<<<nodeb, 256, 0, stream>>>(deg, cnt, perm, pindex, pdeg, alphap, alpha_logit);
    scan_block_kernel<<<NB_SCAN, 256, 0, stream>>>(pdeg, prow, blockSums);
    scan_sums_kernel<<<1, 256, 0, stream>>>(blockSums);
    add_offsets_kernel<<<nodeb, 256, 0, stream>>>(prow, blockSums);
    nodestart_kernel<<<nodeb, 256, 0, stream>>>(perm, prow, node_cursor);
    init_kernel<<<node4b, 256, 0, stream>>>(xu, xi, su, si, norm_bits, pindex, h, h16p, st16p);
    fill_kernel<<<edgeb, 256, 0, stream>>>(es, ed, ew, pindex, node_cursor, csr);

    for (int k = 0; k < K_STEPS; ++k) {
        gather1_kernel<<<node4b, 256, 0, stream>>>(h16p, t16p, csr, prow);
        gather2_update_kernel<<<node4b, 256, 0, stream>>>(t16p, h, h16p, csr, prow,
                                                          perm, st16p, alphap, dt);
    }
}

// Round 5
// 1094.911 us; speedup vs baseline: 17.8746x; 1.1905x over previous
//
#include <hip/hip_runtime.h>

#define N_USERS 100000
#define N_ITEMS 50000
#define N_NODES 150000
#define DIM     32
#define N_EDGES 2400000
#define K_STEPS 10

#define SCAN_CHUNK 1024
#define NB_SCAN ((N_NODES + SCAN_CHUNK - 1) / SCAN_CHUNK)   // 147 blocks
#define WDEQ 3.814697265625e-06f   // 2^-18

typedef float v2f __attribute__((ext_vector_type(2)));

// ---------------- helpers: bf16 / fp8 ----------------
__device__ __forceinline__ float bflo(unsigned u) { return __uint_as_float(u << 16); }
__device__ __forceinline__ float bfhi(unsigned u) { return __uint_as_float(u & 0xffff0000u); }
__device__ __forceinline__ unsigned packbf(float a, float b) {   // RNE pack
    unsigned ua = __float_as_uint(a), ub = __float_as_uint(b);
    ua += 0x7fffu + ((ua >> 16) & 1u);
    ub += 0x7fffu + ((ub >> 16) & 1u);
    return (ua >> 16) | (ub & 0xffff0000u);
}
__device__ __forceinline__ unsigned pack_fp8x4(float a, float b, float c, float d) {
    unsigned r = 0;
    r = __builtin_amdgcn_cvt_pk_fp8_f32(a, b, r, false);   // bytes 0,1
    r = __builtin_amdgcn_cvt_pk_fp8_f32(c, d, r, true);    // bytes 2,3
    return r;
}
// dequant 4 fp8 -> 4 floats
#define UNPACK_FP8X4(d, f0, f1, f2, f3)                          \
    { v2f _lo = __builtin_amdgcn_cvt_pk_f32_fp8((d), false);     \
      v2f _hi = __builtin_amdgcn_cvt_pk_f32_fp8((d), true);      \
      f0 = _lo[0]; f1 = _lo[1]; f2 = _hi[0]; f3 = _hi[1]; }

// ---------------- norm reduction: max over rows of sum(x^2) ----------------
__global__ void norm_kernel(const float* __restrict__ xu, const float* __restrict__ xi,
                            unsigned int* __restrict__ norm_bits) {
    int gid = blockIdx.x * blockDim.x + threadIdx.x;
    int row = gid >> 3;
    int q   = gid & 7;
    float s = 0.0f;
    if (row < N_NODES) {
        const float* x = (row < N_USERS) ? (xu + (size_t)row * DIM)
                                         : (xi + (size_t)(row - N_USERS) * DIM);
        float4 v = *(const float4*)(x + q * 4);
        s = v.x * v.x + v.y * v.y + v.z * v.z + v.w * v.w;
    }
    s += __shfl_xor(s, 1);
    s += __shfl_xor(s, 2);
    s += __shfl_xor(s, 4);
    s = fmaxf(s, __shfl_xor(s, 8));
    s = fmaxf(s, __shfl_xor(s, 16));
    s = fmaxf(s, __shfl_xor(s, 32));
    __shared__ float smax[4];
    int wave = threadIdx.x >> 6;
    if ((threadIdx.x & 63) == 0) smax[wave] = s;
    __syncthreads();
    if (threadIdx.x == 0) {
        float m = fmaxf(fmaxf(smax[0], smax[1]), fmaxf(smax[2], smax[3]));
        atomicMax(norm_bits, __float_as_uint(m));   // non-neg: uint order == float order
    }
}

// --------------------------- degree histogram ------------------------------
__global__ void hist_kernel(const int* __restrict__ ed, int* __restrict__ deg) {
    int e = blockIdx.x * blockDim.x + threadIdx.x;
    if (e >= N_EDGES) return;
    atomicAdd(&deg[ed[e]], 1);
}

// ----------------- degree-bucket counts (64 buckets) -----------------------
__global__ void degcnt_kernel(const int* __restrict__ deg, int* __restrict__ cnt) {
    __shared__ int lc[64];
    if (threadIdx.x < 64) lc[threadIdx.x] = 0;
    __syncthreads();
    int d = blockIdx.x * blockDim.x + threadIdx.x;
    if (d < N_NODES) {
        int dg = deg[d];
        atomicAdd(&lc[dg > 63 ? 63 : dg], 1);
    }
    __syncthreads();
    if (threadIdx.x < 64 && lc[threadIdx.x]) atomicAdd(&cnt[threadIdx.x], lc[threadIdx.x]);
}

// ------------- exclusive scan of the 64 bucket counts (1 wave) -------------
__global__ void scan_cnt_kernel(int* __restrict__ cnt) {
    int tid = threadIdx.x;          // 64 threads = 1 wave
    int v = cnt[tid];
    int inc = v;
    for (int off = 1; off < 64; off <<= 1) {
        int t = __shfl_up(inc, off);
        if (tid >= off) inc += t;
    }
    cnt[tid] = inc - v;             // exclusive offset; ticket advances it
}

// --- ticket: degree-sorted permutation. perm[pos]=node, pindex[node]=pos ---
__global__ void ticket_kernel(const int* __restrict__ deg, int* __restrict__ cnt,
                              int* __restrict__ perm, int* __restrict__ pindex,
                              int* __restrict__ pdeg, float* __restrict__ alphap,
                              const float* __restrict__ alpha_logit) {
    __shared__ int lcnt[64];
    __shared__ int lbase[64];
    int tid = threadIdx.x;
    if (tid < 64) lcnt[tid] = 0;
    __syncthreads();
    int d = blockIdx.x * blockDim.x + tid;
    int b = 0, rank = 0, dg = 0;
    if (d < N_NODES) {
        dg = deg[d];
        b = dg > 63 ? 63 : dg;
        rank = atomicAdd(&lcnt[b], 1);
    }
    __syncthreads();
    if (tid < 64 && lcnt[tid]) lbase[tid] = atomicAdd(&cnt[tid], lcnt[tid]);
    __syncthreads();
    if (d < N_NODES) {
        int pos = lbase[b] + rank;
        perm[pos] = d;
        pindex[d] = pos;
        pdeg[pos] = dg;
        alphap[pos] = 1.0f / (1.0f + __expf(-alpha_logit[d]));
    }
}

// ------------- per-block exclusive scan over pdeg (1024/block) -------------
__global__ void scan_block_kernel(const int* __restrict__ pdeg, int* __restrict__ excl,
                                  int* __restrict__ blockSums) {
    int base = blockIdx.x * SCAN_CHUNK + threadIdx.x * 4;
    int v0 = 0, v1 = 0, v2 = 0, v3 = 0;
    if (base + 3 < N_NODES) {
        int4 t = *(const int4*)(pdeg + base);
        v0 = t.x; v1 = t.y; v2 = t.z; v3 = t.w;
    } else {
        if (base + 0 < N_NODES) v0 = pdeg[base + 0];
        if (base + 1 < N_NODES) v1 = pdeg[base + 1];
        if (base + 2 < N_NODES) v2 = pdeg[base + 2];
    }
    int s = v0 + v1 + v2 + v3;
    int lane = threadIdx.x & 63;
    int inc = s;
    for (int off = 1; off < 64; off <<= 1) {
        int t = __shfl_up(inc, off);
        if (lane >= off) inc += t;
    }
    __shared__ int wsum[4];
    int wave = threadIdx.x >> 6;
    if (lane == 63) wsum[wave] = inc;
    __syncthreads();
    int woff = 0;
    for (int w = 0; w < 4; ++w) if (w < wave) woff += wsum[w];
    int excl_thread = woff + inc - s;
    if (base + 0 < N_NODES) excl[base + 0] = excl_thread;
    if (base + 1 < N_NODES) excl[base + 1] = excl_thread + v0;
    if (base + 2 < N_NODES) excl[base + 2] = excl_thread + v0 + v1;
    if (base + 3 < N_NODES) excl[base + 3] = excl_thread + v0 + v1 + v2;
    if (threadIdx.x == 255) blockSums[blockIdx.x] = woff + inc;
}

__global__ void scan_sums_kernel(int* __restrict__ blockSums) {
    __shared__ int buf[256];
    int tid = threadIdx.x;
    int v = (tid < NB_SCAN) ? blockSums[tid] : 0;
    buf[tid] = v;
    __syncthreads();
    for (int off = 1; off < 256; off <<= 1) {
        int t = (tid >= off) ? buf[tid - off] : 0;
        __syncthreads();
        buf[tid] += t;
        __syncthreads();
    }
    if (tid < NB_SCAN) blockSums[tid] = buf[tid] - v;   // exclusive
}

// prow[i] += blockoffset; sentinel prow[N_NODES] = N_EDGES
__global__ void add_offsets_kernel(int* __restrict__ prow, const int* __restrict__ blockSums) {
    int i = blockIdx.x * blockDim.x + threadIdx.x;
    if (i == 0) prow[N_NODES] = N_EDGES;
    if (i >= N_NODES) return;
    prow[i] += blockSums[i >> 10];
}

// node_cursor[node] = permuted row start (for fill's ticketing)
__global__ void nodestart_kernel(const int* __restrict__ perm, const int* __restrict__ prow,
                                 int* __restrict__ node_cursor) {
    int i = blockIdx.x * blockDim.x + threadIdx.x;
    if (i >= N_NODES) return;
    node_cursor[perm[i]] = prow[i];
}

// --- init: h(d_out) = x/norm; permuted fp8 mirror h8p; bf16 st16p ----------
// 8 lanes per node; lane q owns floats [q*4, q*4+4).
__global__ void init_kernel(const float* __restrict__ xu, const float* __restrict__ xi,
                            const float* __restrict__ su, const float* __restrict__ si,
                            const unsigned int* __restrict__ norm_bits,
                            const int* __restrict__ pindex,
                            float* __restrict__ h, unsigned* __restrict__ h8p,
                            unsigned* __restrict__ st16p) {
    int gid = blockIdx.x * blockDim.x + threadIdx.x;
    int d = gid >> 3;
    int q = gid & 7;
    if (d >= N_NODES) return;
    float rn = rsqrtf(__uint_as_float(*norm_bits));
    int fbase = d * DIM + (q << 2);
    const float* x = (d < N_USERS) ? (xu + fbase) : (xi + fbase - N_USERS * DIM);
    const float* s = (d < N_USERS) ? (su + fbase) : (si + fbase - N_USERS * DIM);
    float4 v = *(const float4*)x;
    v.x *= rn; v.y *= rn; v.z *= rn; v.w *= rn;
    *(float4*)(h + fbase) = v;
    int i = pindex[d];
    h8p[(i << 3) + q] = pack_fp8x4(v.x, v.y, v.z, v.w);
    float4 sv = *(const float4*)s;
    uint2 sp;
    sp.x = packbf(sv.x * rn, sv.y * rn);
    sp.y = packbf(sv.z * rn, sv.w * rn);
    *(uint2*)(st16p + (i << 4) + (q << 1)) = sp;
}

// -- fill: CSR entry = (pindex[src] << 14) | q14 at permuted row position ---
__global__ void fill_kernel(const int* __restrict__ es, const int* __restrict__ ed,
                            const float* __restrict__ ew, const int* __restrict__ pindex,
                            int* __restrict__ node_cursor, unsigned* __restrict__ csr) {
    int e = blockIdx.x * blockDim.x + threadIdx.x;
    if (e >= N_EDGES) return;
    int d = ed[e];
    int pos = atomicAdd(&node_cursor[d], 1);
    unsigned q = (unsigned)(ew[e] * 262144.0f + 0.5f);   // w in [0,1/16): q < 16384
    if (q > 16383u) q = 16383u;
    csr[pos] = ((unsigned)pindex[es[e]] << 14) | q;
}

// ---- hop-1 gather: t8p[i] = fp8( sum w * fp8row(h8p[psrc]) ) --------------
// 8 lanes/node, 1 dword (4 fp8) per lane per edge, unroll 4.
__global__ void gather1_kernel(const unsigned* __restrict__ h8p,
                               unsigned* __restrict__ t8p,
                               const unsigned* __restrict__ csr,
                               const int* __restrict__ prow) {
    int gid = blockIdx.x * blockDim.x + threadIdx.x;
    int i = gid >> 3;
    int q = gid & 7;
    if (i >= N_NODES) return;
    int j   = prow[i];
    int end = prow[i + 1];
    float a0 = 0, a1 = 0, a2 = 0, a3 = 0;
    for (; j + 4 <= end; j += 4) {
        unsigned e0 = __builtin_nontemporal_load(csr + j);
        unsigned e1 = __builtin_nontemporal_load(csr + j + 1);
        unsigned e2 = __builtin_nontemporal_load(csr + j + 2);
        unsigned e3 = __builtin_nontemporal_load(csr + j + 3);
        float w0 = (float)(e0 & 0x3fffu) * WDEQ;
        float w1 = (float)(e1 & 0x3fffu) * WDEQ;
        float w2 = (float)(e2 & 0x3fffu) * WDEQ;
        float w3 = (float)(e3 & 0x3fffu) * WDEQ;
        unsigned d0 = h8p[((e0 >> 14) << 3) + q];
        unsigned d1 = h8p[((e1 >> 14) << 3) + q];
        unsigned d2 = h8p[((e2 >> 14) << 3) + q];
        unsigned d3 = h8p[((e3 >> 14) << 3) + q];
        float f0, f1, f2, f3;
        UNPACK_FP8X4(d0, f0, f1, f2, f3);
        a0 = fmaf(w0, f0, a0); a1 = fmaf(w0, f1, a1);
        a2 = fmaf(w0, f2, a2); a3 = fmaf(w0, f3, a3);
        UNPACK_FP8X4(d1, f0, f1, f2, f3);
        a0 = fmaf(w1, f0, a0); a1 = fmaf(w1, f1, a1);
        a2 = fmaf(w1, f2, a2); a3 = fmaf(w1, f3, a3);
        UNPACK_FP8X4(d2, f0, f1, f2, f3);
        a0 = fmaf(w2, f0, a0); a1 = fmaf(w2, f1, a1);
        a2 = fmaf(w2, f2, a2); a3 = fmaf(w2, f3, a3);
        UNPACK_FP8X4(d3, f0, f1, f2, f3);
        a0 = fmaf(w3, f0, a0); a1 = fmaf(w3, f1, a1);
        a2 = fmaf(w3, f2, a2); a3 = fmaf(w3, f3, a3);
    }
    for (; j < end; ++j) {
        unsigned e0 = __builtin_nontemporal_load(csr + j);
        float w0 = (float)(e0 & 0x3fffu) * WDEQ;
        unsigned d0 = h8p[((e0 >> 14) << 3) + q];
        float f0, f1, f2, f3;
        UNPACK_FP8X4(d0, f0, f1, f2, f3);
        a0 = fmaf(w0, f0, a0); a1 = fmaf(w0, f1, a1);
        a2 = fmaf(w0, f2, a2); a3 = fmaf(w0, f3, a3);
    }
    t8p[(i << 3) + q] = pack_fp8x4(a0, a1, a2, a3);
}

// ---- hop-2 gather + update; h stays fp32 node-indexed in d_out ------------
__global__ void gather2_update_kernel(const unsigned* __restrict__ t8p,
                                      float* __restrict__ h,
                                      unsigned* __restrict__ h8p,
                                      const unsigned* __restrict__ csr,
                                      const int* __restrict__ prow,
                                      const int* __restrict__ perm,
                                      const unsigned* __restrict__ st16p,
                                      const float* __restrict__ alphap,
                                      const float* __restrict__ dt) {
    int gid = blockIdx.x * blockDim.x + threadIdx.x;
    int i = gid >> 3;
    int q = gid & 7;
    if (i >= N_NODES) return;
    int j   = prow[i];
    int end = prow[i + 1];
    float a0 = 0, a1 = 0, a2 = 0, a3 = 0;
    for (; j + 4 <= end; j += 4) {
        unsigned e0 = __builtin_nontemporal_load(csr + j);
        unsigned e1 = __builtin_nontemporal_load(csr + j + 1);
        unsigned e2 = __builtin_nontemporal_load(csr + j + 2);
        unsigned e3 = __builtin_nontemporal_load(csr + j + 3);
        float w0 = (float)(e0 & 0x3fffu) * WDEQ;
        float w1 = (float)(e1 & 0x3fffu) * WDEQ;
        float w2 = (float)(e2 & 0x3fffu) * WDEQ;
        float w3 = (float)(e3 & 0x3fffu) * WDEQ;
        unsigned d0 = t8p[((e0 >> 14) << 3) + q];
        unsigned d1 = t8p[((e1 >> 14) << 3) + q];
        unsigned d2 = t8p[((e2 >> 14) << 3) + q];
        unsigned d3 = t8p[((e3 >> 14) << 3) + q];
        float f0, f1, f2, f3;
        UNPACK_FP8X4(d0, f0, f1, f2, f3);
        a0 = fmaf(w0, f0, a0); a1 = fmaf(w0, f1, a1);
        a2 = fmaf(w0, f2, a2); a3 = fmaf(w0, f3, a3);
        UNPACK_FP8X4(d1, f0, f1, f2, f3);
        a0 = fmaf(w1, f0, a0); a1 = fmaf(w1, f1, a1);
        a2 = fmaf(w1, f2, a2); a3 = fmaf(w1, f3, a3);
        UNPACK_FP8X4(d2, f0, f1, f2, f3);
        a0 = fmaf(w2, f0, a0); a1 = fmaf(w2, f1, a1);
        a2 = fmaf(w2, f2, a2); a3 = fmaf(w2, f3, a3);
        UNPACK_FP8X4(d3, f0, f1, f2, f3);
        a0 = fmaf(w3, f0, a0); a1 = fmaf(w3, f1, a1);
        a2 = fmaf(w3, f2, a2); a3 = fmaf(w3, f3, a3);
    }
    for (; j < end; ++j) {
        unsigned e0 = __builtin_nontemporal_load(csr + j);
        float w0 = (float)(e0 & 0x3fffu) * WDEQ;
        unsigned d0 = t8p[((e0 >> 14) << 3) + q];
        float f0, f1, f2, f3;
        UNPACK_FP8X4(d0, f0, f1, f2, f3);
        a0 = fmaf(w0, f0, a0); a1 = fmaf(w0, f1, a1);
        a2 = fmaf(w0, f2, a2); a3 = fmaf(w0, f3, a3);
    }
    float step = dt[0] * (1.0f / K_STEPS);
    float al = alphap[i];
    int d = perm[i];
    int fbase = d * DIM + (q << 2);
    float4 hv = *(const float4*)(h + fbase);
    uint2 sp = *(const uint2*)(st16p + (i << 4) + (q << 1));
    hv.x += step * (a0 - al * hv.x + bflo(sp.x));
    hv.y += step * (a1 - al * hv.y + bfhi(sp.x));
    hv.z += step * (a2 - al * hv.z + bflo(sp.y));
    hv.w += step * (a3 - al * hv.w + bfhi(sp.y));
    *(float4*)(h + fbase) = hv;
    h8p[(i << 3) + q] = pack_fp8x4(hv.x, hv.y, hv.z, hv.w);
}

extern "C" void kernel_launch(void* const* d_in, const int* in_sizes, int n_in,
                              void* d_out, int out_size, void* d_ws, size_t ws_size,
                              hipStream_t stream) {
    const float* xu          = (const float*)d_in[0];
    const float* xi          = (const float*)d_in[1];
    const float* su          = (const float*)d_in[2];
    const float* si          = (const float*)d_in[3];
    const float* ew          = (const float*)d_in[4];
    const float* alpha_logit = (const float*)d_in[5];
    const float* dt          = (const float*)d_in[6];
    const int*   es          = (const int*)d_in[7];
    const int*   ed          = (const int*)d_in[8];
    float* h = (float*)d_out;                     // fp32 h lives in d_out (node order)

    // ---- workspace layout (~34 MB) ----
    char* base = (char*)d_ws;
    unsigned int* norm_bits = (unsigned int*)base;              // 4 B
    int* cnt       = (int*)(base + 64);                         // 64 ints
    int* blockSums = (int*)(base + 512);                        // 256 ints
    const size_t SLOT = 640 * 1024;                             // 640 KB slots
    int*   deg         = (int*)(base + 4096 + 0 * SLOT);
    int*   perm        = (int*)(base + 4096 + 1 * SLOT);
    int*   pindex      = (int*)(base + 4096 + 2 * SLOT);
    int*   pdeg        = (int*)(base + 4096 + 3 * SLOT);
    int*   prow        = (int*)(base + 4096 + 4 * SLOT);        // N_NODES+1 entries
    int*   node_cursor = (int*)(base + 4096 + 5 * SLOT);
    float* alphap      = (float*)(base + 4096 + 6 * SLOT);
    unsigned* csr   = (unsigned*)(base + 5u * 1024 * 1024);     // 9.6 MB
    unsigned* t8p   = csr + N_EDGES;                            // 4.8 MB (fp8 rows)
    unsigned* h8p   = t8p + (size_t)N_NODES * 8;                // 4.8 MB (fp8 rows)
    unsigned* st16p = h8p + (size_t)N_NODES * 8;                // 9.6 MB (bf16 rows)

    hipMemsetAsync(norm_bits, 0, sizeof(unsigned int), stream);
    hipMemsetAsync(cnt, 0, 64 * sizeof(int), stream);
    hipMemsetAsync(deg, 0, (size_t)N_NODES * sizeof(int), stream);

    const int nodeb  = (N_NODES + 255) / 256;
    const int edgeb  = (N_EDGES + 255) / 256;
    const int node8b = (N_NODES * 8 + 255) / 256;

    norm_kernel<<<(N_NODES * 8 + 255) / 256, 256, 0, stream>>>(xu, xi, norm_bits);
    hist_kernel<<<edgeb, 256, 0, stream>>>(ed, deg);
    degcnt_kernel<<<nodeb, 256, 0, stream>>>(deg, cnt);
    scan_cnt_kernel<<<1, 64, 0, stream>>>(cnt);
    ticket_kernel<<<nodeb, 256, 0, stream>>>(deg, cnt, perm, pindex, pdeg, alphap, alpha_logit);
    scan_block_kernel<<<NB_SCAN, 256, 0, stream>>>(pdeg, prow, blockSums);
    scan_sums_kernel<<<1, 256, 0, stream>>>(blockSums);
    add_offsets_kernel<<<nodeb, 256, 0, stream>>>(prow, blockSums);
    nodestart_kernel<<<nodeb, 256, 0, stream>>>(perm, prow, node_cursor);
    init_kernel<<<node8b, 256, 0, stream>>>(xu, xi, su, si, norm_bits, pindex, h, h8p, st16p);
    fill_kernel<<<edgeb, 256, 0, stream>>>(es, ed, ew, pindex, node_cursor, csr);

    for (int k = 0; k < K_STEPS; ++k) {
        gather1_kernel<<<node8b, 256, 0, stream>>>(h8p, t8p, csr, prow);
        gather2_update_kernel<<<node8b, 256, 0, stream>>>(t8p, h, h8p, csr, prow,
                                                          perm, st16p, alphap, dt);
    }
}